// Round 10
// baseline (427.989 us; speedup 1.0000x reference)
//
#include <hip/hip_runtime.h>
#include <math.h>

// Problem constants (from reference)
#define NNODES 100000
#define NREL 500
#define E1 288000
#define ETOT 320000
#define LALPHA 0.2f
#define SEPS 1e-16f
#define NB_SCAN ((NNODES + 255) / 256)  // 391 blocks of 256 for the scan
#define GTILES 6250                      // 100000 / 16 row-tiles, exact
#define GTPB 5                           // tiles per block
#define GGRID (GTILES / GTPB)            // 1250 blocks, exact

typedef __attribute__((ext_vector_type(8))) short bf16x8;
typedef __attribute__((ext_vector_type(4))) float f32x4;

// fp32 -> bf16 (round-to-nearest-even), header-independent
__device__ __forceinline__ unsigned short f2bf(float x) {
  unsigned int u = __float_as_uint(x);
  unsigned int r = (u + 0x7fffu + ((u >> 16) & 1u)) >> 16;
  return (unsigned short)r;
}
// pack two fp32 as bf16 pair (lo, hi) in one uint
__device__ __forceinline__ unsigned int packbf2(float lo, float hi) {
  return (unsigned int)f2bf(lo) | ((unsigned int)f2bf(hi) << 16);
}
__device__ __forceinline__ float unpk_lo(unsigned int u) { return __uint_as_float(u << 16); }
__device__ __forceinline__ float unpk_hi(unsigned int u) {
  return __uint_as_float(u & 0xffff0000u);
}
__device__ __forceinline__ float lrelu(float e) { return (e >= 0.f) ? e : LALPHA * e; }
// clamped exp: shift-free softmax weight (logits here are O(1); clamp only for safety)
__device__ __forceinline__ float wexp(float lg) { return __expf(fminf(lg, 60.f)); }

// ---------------- wave (64-lane) reductions ----------------
__device__ __forceinline__ float wave_sum64(float v) {
#pragma unroll
  for (int o = 32; o >= 1; o >>= 1) v += __shfl_xor(v, o, 64);
  return v;
}
// reduce across the 16 lanes of a colv-group (bits 0..3)
__device__ __forceinline__ float red16(float v) {
  v += __shfl_xor(v, 1, 64);
  v += __shfl_xor(v, 2, 64);
  v += __shfl_xor(v, 4, 64);
  v += __shfl_xor(v, 8, 64);
  return v;
}

// ---------------- CSR build ----------------
__global__ void k_zero_int(int* __restrict__ p, int n) {
  int i = blockIdx.x * blockDim.x + threadIdx.x;
  if (i < n) p[i] = 0;
}

__global__ void k_count(const int* __restrict__ src, int* __restrict__ cnt) {
  int e = blockIdx.x * blockDim.x + threadIdx.x;
  if (e < ETOT) atomicAdd(&cnt[src[e]], 1);
}

__global__ void k_scan_a(const int* __restrict__ cnt, int* __restrict__ rowstart,
                         int* __restrict__ blockTot) {
  __shared__ int s[256];
  int t = threadIdx.x;
  int idx = blockIdx.x * 256 + t;
  int v = (idx < NNODES) ? cnt[idx] : 0;
  s[t] = v;
  __syncthreads();
  for (int off = 1; off < 256; off <<= 1) {
    int xv = (t >= off) ? s[t - off] : 0;
    __syncthreads();
    s[t] += xv;
    __syncthreads();
  }
  if (idx < NNODES) rowstart[idx] = s[t] - v;  // exclusive within block
  if (t == 255) blockTot[blockIdx.x] = s[255];
}

__global__ void k_scan_b(const int* __restrict__ blockTot, int* __restrict__ blockOff) {
  __shared__ int s[512];
  int t = threadIdx.x;
  int v = (t < NB_SCAN) ? blockTot[t] : 0;
  s[t] = v;
  __syncthreads();
  for (int off = 1; off < 512; off <<= 1) {
    int xv = (t >= off) ? s[t - off] : 0;
    __syncthreads();
    s[t] += xv;
    __syncthreads();
  }
  if (t < NB_SCAN) blockOff[t] = s[t] - v;  // exclusive
}

__global__ void k_scan_c(int* __restrict__ rowstart, const int* __restrict__ blockOff,
                         int* __restrict__ cursor) {
  int idx = blockIdx.x * 256 + threadIdx.x;
  if (idx < NNODES) {
    int v = rowstart[idx] + blockOff[blockIdx.x];
    rowstart[idx] = v;
    cursor[idx] = v;
  }
  if (idx == 0) rowstart[NNODES] = ETOT;
}

__global__ void k_scatter(const int* __restrict__ src, int* __restrict__ cursor,
                          int* __restrict__ perm) {
  int e = blockIdx.x * blockDim.x + threadIdx.x;
  if (e < ETOT) {
    int pos = atomicAdd(&cursor[src[e]], 1);
    perm[pos] = e;
  }
}

// ---------------- relation-level precompute ----------------
// rW1p[t][j] = bf16pair(rel[2j], rel[2j+1]), rel = concat(h0 64, h1 64)  (plain layout)
__global__ void k_relprep1(const float* __restrict__ r, const float* __restrict__ Wh,
                           const float* __restrict__ ah, unsigned int* __restrict__ rW1p,
                           float* __restrict__ srel1) {
  __shared__ float vals[128];
  int t = blockIdx.x;    // 0..499
  int tid = threadIdx.x; // 0..127: h = tid>>6, kk = tid&63
  int h = tid >> 6, kk = tid & 63;
  const float* wcol = Wh + h * 24576 + 256 * 64 + kk;
  const float* rrow = r + t * 128;
  float acc = 0.f;
#pragma unroll 4
  for (int d = 0; d < 128; ++d) acc = fmaf(rrow[d], wcol[d * 64], acc);
  vals[tid] = acc;
  float p = wave_sum64(acc * ah[h * 64 + kk]);
  if (kk == 0) srel1[t * 2 + h] = p;
  __syncthreads();
  if (tid < 64) rW1p[t * 64 + tid] = packbf2(vals[2 * tid], vals[2 * tid + 1]);
}

// Fused: r2[t] row (to r2out, LDS) + rW2p pack + srel2
__global__ void k_relprep2f(const float* __restrict__ r, const float* __restrict__ Wr,
                            const float* __restrict__ Wo, const float* __restrict__ ao,
                            unsigned int* __restrict__ rW2p, float* __restrict__ srel2,
                            float* __restrict__ r2out) {
  __shared__ float v2[128];
  __shared__ float s[128];
  __shared__ float vals[128];
  int t = blockIdx.x;   // 0..499
  int k = threadIdx.x;  // 0..127
  // phase A: r2 row
  float a2 = 0.f;
#pragma unroll 4
  for (int d = 0; d < 128; ++d) a2 = fmaf(r[t * 128 + d], Wr[d * 128 + k], a2);
  r2out[t * 128 + k] = a2;
  v2[k] = a2;
  __syncthreads();
  // phase B: rW2 = r2 @ Wo[256:384]
  float acc = 0.f;
#pragma unroll 4
  for (int d = 0; d < 128; ++d) acc = fmaf(v2[d], Wo[(256 + d) * 128 + k], acc);
  vals[k] = acc;
  s[k] = acc * ao[k];
  __syncthreads();
  for (int off = 64; off >= 1; off >>= 1) {
    if (k < off) s[k] += s[k + off];
    __syncthreads();
  }
  if (k == 0) srel2[t] = s[0];
  if (k < 64) rW2p[t * 64 + k] = packbf2(vals[2 * k], vals[2 * k + 1]);
}

// ---------------- MFMA weight packing (both layers, one launch) ----------------
// col order: LAYER1 c = part*128 + h*64 + kc; LAYER2 c = part*128 + kc
__global__ void k_packb_both(const float* __restrict__ Wh, const float* __restrict__ Wo,
                             unsigned short* __restrict__ Wb1,
                             unsigned short* __restrict__ Wb2) {
  int c = blockIdx.x & 255;
  int layer = blockIdx.x >> 8;
  int d = threadIdx.x;  // 0..127
  if (layer == 0) {
    int h = (c >> 6) & 1, part = c >> 7, kc = c & 63;
    Wb1[c * 128 + d] = f2bf(Wh[h * 24576 + (part * 128 + d) * 64 + kc]);
  } else {
    int part = c >> 7, kc = c & 127;
    Wb2[c * 128 + d] = f2bf(Wo[(part * 128 + d) * 128 + kc]);
  }
}

// ---------------- MFMA GEMM: xWp[N][128 uints] (plain bf16 row) = X @ Wb^T ----------------
// Wave owns 64 CONTIGUOUS cols; B resident in 64 VGPR. No LDS/barriers/atomics.
// Per row, wave writes one aligned 128-B chunk. sc slot direct-stored per wave.
template <int LAYER>
__global__ __launch_bounds__(256) void k_gemm_mfma(const void* __restrict__ Xin,
                                                   const unsigned short* __restrict__ Wb,
                                                   const float* __restrict__ avec,
                                                   unsigned int* __restrict__ xWp,
                                                   float* __restrict__ sc) {
  const int lane = threadIdx.x & 63;
  const int wave = threadIdx.x >> 6;
  const int colv = lane & 15;
  const int kg = lane >> 4;

  bf16x8 b[4][4];
#pragma unroll
  for (int t = 0; t < 4; ++t)
#pragma unroll
    for (int s = 0; s < 4; ++s)
      b[t][s] = *(const bf16x8*)(Wb + (size_t)(wave * 64 + t * 16 + colv) * 128 + s * 32 +
                                 kg * 8);
  float av[4];
#pragma unroll
  for (int t = 0; t < 4; ++t) av[t] = avec[(wave & 1) * 64 + t * 16 + colv];
  const int slot = (LAYER == 1) ? (((wave & 1) << 1) | (wave >> 1)) : wave;

  const float4* xf4 = (const float4*)Xin;
  const uint4* xu4 = (const uint4*)Xin;
  int tile = blockIdx.x * GTPB;

  float4 cf[8];
  uint4 cu[4];
  {
    int ar = tile * 16 + colv;
    if (LAYER == 1) {
      int base = ar * 32 + kg * 2;
#pragma unroll
      for (int s = 0; s < 4; ++s) {
        cf[2 * s] = xf4[base + s * 8];
        cf[2 * s + 1] = xf4[base + s * 8 + 1];
      }
    } else {
      int base = ar * 16 + kg;
#pragma unroll
      for (int s = 0; s < 4; ++s) cu[s] = xu4[base + s * 4];
    }
  }

  for (int it = 0; it < GTPB; ++it, ++tile) {
    float4 nf[8];
    uint4 nu[4];
    const bool hasnext = (it + 1 < GTPB);
    if (hasnext) {
      int ar = (tile + 1) * 16 + colv;
      if (LAYER == 1) {
        int base = ar * 32 + kg * 2;
#pragma unroll
        for (int s = 0; s < 4; ++s) {
          nf[2 * s] = xf4[base + s * 8];
          nf[2 * s + 1] = xf4[base + s * 8 + 1];
        }
      } else {
        int base = ar * 16 + kg;
#pragma unroll
        for (int s = 0; s < 4; ++s) nu[s] = xu4[base + s * 4];
      }
    }

    bf16x8 a[4];
    if (LAYER == 1) {
#pragma unroll
      for (int s = 0; s < 4; ++s) {
        union {
          unsigned short us[8];
          bf16x8 v;
        } u;
        u.us[0] = f2bf(cf[2 * s].x); u.us[1] = f2bf(cf[2 * s].y);
        u.us[2] = f2bf(cf[2 * s].z); u.us[3] = f2bf(cf[2 * s].w);
        u.us[4] = f2bf(cf[2 * s + 1].x); u.us[5] = f2bf(cf[2 * s + 1].y);
        u.us[6] = f2bf(cf[2 * s + 1].z); u.us[7] = f2bf(cf[2 * s + 1].w);
        a[s] = u.v;
      }
    } else {
#pragma unroll
      for (int s = 0; s < 4; ++s) {
        union {
          uint4 q;
          bf16x8 v;
        } u;
        u.q = cu[s];
        a[s] = u.v;
      }
    }

    f32x4 acc[4];
#pragma unroll
    for (int t = 0; t < 4; ++t) acc[t] = (f32x4){0.f, 0.f, 0.f, 0.f};
#pragma unroll
    for (int s = 0; s < 4; ++s)
#pragma unroll
      for (int t = 0; t < 4; ++t)
        acc[t] = __builtin_amdgcn_mfma_f32_16x16x32_bf16(a[s], b[t][s], acc[t], 0, 0, 0);

    const int rbase = tile * 16 + kg * 4;
    const int m = colv >> 1;
    const bool evn = (colv & 1) == 0;
#pragma unroll
    for (int i = 0; i < 4; ++i) {
      unsigned int* orow = xWp + (size_t)(rbase + i) * 128 + wave * 32;
#pragma unroll
      for (int t = 0; t < 4; ++t) {
        float lo = acc[t][i];
        float other = __shfl_xor(lo, 1, 64);
        if (evn) orow[t * 8 + m] = packbf2(lo, other);
      }
      float p = 0.f;
#pragma unroll
      for (int t = 0; t < 4; ++t) p = fmaf(acc[t][i], av[t], p);
      p = red16(p);
      if (colv == 0) sc[(size_t)(rbase + i) * 4 + slot] = p;
    }

    if (hasnext) {
      if (LAYER == 1) {
#pragma unroll
        for (int j = 0; j < 8; ++j) cf[j] = nf[j];
      } else {
#pragma unroll
        for (int j = 0; j < 4; ++j) cu[j] = nu[j];
      }
    }
  }
}

// ---------------- edge-parallel: logits -> exp weights + denom atomics ----------------
__global__ void k_eprep1(const int* __restrict__ perm, const int* __restrict__ srcA,
                         const int* __restrict__ dstA, const int* __restrict__ et,
                         const int* __restrict__ et2, const float* __restrict__ sc1,
                         const float* __restrict__ srel1, int* __restrict__ srcp,
                         int* __restrict__ dnp, int2* __restrict__ t12,
                         float2* __restrict__ wexp1, float* __restrict__ denom1) {
  int p = blockIdx.x * 256 + threadIdx.x;
  if (p >= ETOT) return;
  int ed = perm[p];
  int src = srcA[ed], dn = dstA[ed];
  int t1, t2 = -1;
  float rel0, rel1;
  if (ed < E1) {
    t1 = et[ed];
    float2 sr = ((const float2*)srel1)[t1];
    rel0 = sr.x;
    rel1 = sr.y;
  } else {
    int2 tt = ((const int2*)et2)[ed - E1];
    t1 = tt.x;
    t2 = tt.y;
    float2 sa = ((const float2*)srel1)[t1];
    float2 sb = ((const float2*)srel1)[t2];
    rel0 = sa.x + sb.x;
    rel1 = sa.y + sb.y;
  }
  // sc1[n] = {ss_h0, sd_h0, ss_h1, sd_h1}
  float4 ssv = ((const float4*)sc1)[src];
  float4 sdv = ((const float4*)sc1)[dn];
  float w0 = wexp(lrelu(ssv.x + sdv.y + rel0));
  float w1 = wexp(lrelu(ssv.z + sdv.w + rel1));
  wexp1[p] = make_float2(w0, w1);
  atomicAdd(&denom1[2 * src], w0);
  atomicAdd(&denom1[2 * src + 1], w1);
  srcp[p] = src;
  dnp[p] = dn;
  t12[p] = make_int2(t1, t2);
}

// sc2[n] = {p0a, p0b, p1a, p1b}: ss = p0a+p0b, sd = p1a+p1b
__global__ void k_eprep2(const int* __restrict__ srcp, const int* __restrict__ dnp,
                         const int2* __restrict__ t12, const float* __restrict__ sc2,
                         const float* __restrict__ srel2, float* __restrict__ wexp2,
                         float* __restrict__ denom2) {
  int p = blockIdx.x * 256 + threadIdx.x;
  if (p >= ETOT) return;
  int src = srcp[p], dn = dnp[p];
  int2 tt = t12[p];
  float rel = srel2[tt.x];
  if (tt.y >= 0) rel += srel2[tt.y];
  float4 ssv = ((const float4*)sc2)[src];
  float4 sdv = ((const float4*)sc2)[dn];
  float w = wexp(lrelu((ssv.x + ssv.y) + (sdv.z + sdv.w) + rel));
  wexp2[p] = w;
  atomicAdd(&denom2[src], w);
}

// ---------------- layer-1 aggregation: pure weighted gather (no in-wave softmax) ----------
// Plain layout: uint j of a row = cols (2j, 2j+1). k<2 -> head0 cols, k>=2 -> head1.
__global__ __launch_bounds__(256) void k_agg1(
    const int* __restrict__ rowstart, const float2* __restrict__ wexp1,
    const int* __restrict__ dnp, const int2* __restrict__ t12,
    const unsigned int* __restrict__ xWp, const unsigned int* __restrict__ rW1p,
    const float2* __restrict__ denom1, unsigned int* __restrict__ x1b) {
  int n = blockIdx.x * 4 + (threadIdx.x >> 6);
  int lane = threadIdx.x & 63;
  int q = lane & 15, g = lane >> 4;
  int s0 = rowstart[n];
  int deg = rowstart[n + 1] - s0;
  int jj = q + 16 * g;
  float r0 = 0.f, r1 = 0.f;
  if (deg > 0) {
    float ac0[4] = {0.f, 0.f, 0.f, 0.f}, ac1[4] = {0.f, 0.f, 0.f, 0.f};
    const int pend = s0 + deg;
    for (int p0 = s0; p0 < pend; p0 += 4) {
      int p = p0 + g;  // this group's edge
      float w0 = 0.f, w1 = 0.f;
      int dne = 0, t1e = 0, t2e = -1;
      if (p < pend) {
        float2 wv = wexp1[p];  // 16-lane same-address broadcast loads
        w0 = wv.x;
        w1 = wv.y;
        dne = dnp[p];
        int2 tt = t12[p];
        t1e = tt.x;
        t2e = tt.y;
      }
      const unsigned int* xr = xWp + (size_t)dne * 128 + 64;
      const unsigned int* rp = rW1p + (size_t)t1e * 64;
#pragma unroll
      for (int k = 0; k < 4; ++k) {
        int j2 = q + 16 * k;
        float as = (k < 2) ? w0 : w1;  // head by col range (compile-time per k)
        unsigned int ud = xr[j2];
        unsigned int ur = rp[j2];
        float rv0 = unpk_lo(ur), rv1 = unpk_hi(ur);
        if (t2e >= 0) {  // group-uniform branch
          unsigned int u2 = rW1p[(size_t)t2e * 64 + j2];
          rv0 += unpk_lo(u2);
          rv1 += unpk_hi(u2);
        }
        ac0[k] = fmaf(as, unpk_lo(ud) + rv0, ac0[k]);
        ac1[k] = fmaf(as, unpk_hi(ud) + rv1, ac1[k]);
      }
    }
    // reduce across the 4 groups (lanes q, q+16, q+32, q+48)
#pragma unroll
    for (int k = 0; k < 4; ++k) {
      ac0[k] += __shfl_xor(ac0[k], 16, 64);
      ac0[k] += __shfl_xor(ac0[k], 32, 64);
      ac1[k] += __shfl_xor(ac1[k], 16, 64);
      ac1[k] += __shfl_xor(ac1[k], 32, 64);
    }
    float a0g = (g == 0) ? ac0[0] : (g == 1) ? ac0[1] : (g == 2) ? ac0[2] : ac0[3];
    float a1g = (g == 0) ? ac1[0] : (g == 1) ? ac1[1] : (g == 2) ? ac1[2] : ac1[3];
    float2 dd = denom1[n];
    float dsel = (g < 2) ? dd.x : dd.y;
    float isel = 1.f / (dsel + SEPS);
    unsigned int us = xWp[(size_t)n * 128 + jj];
    float o0 = (a0g + dsel * unpk_lo(us)) * isel;
    float o1 = (a1g + dsel * unpk_hi(us)) * isel;
    r0 = (o0 > 0.f) ? o0 : __expf(o0) - 1.f;  // elu (concat=True)
    r1 = (o1 > 0.f) ? o1 : __expf(o1) - 1.f;
  }
  x1b[(size_t)n * 64 + jj] = packbf2(r0, r1);  // plain bf16 row (cols 2jj, 2jj+1)
}

// ---------------- layer-2 aggregation: same structure, fp32 out ----------------
__global__ __launch_bounds__(256) void k_agg2(
    const int* __restrict__ rowstart, const float* __restrict__ wexp2,
    const int* __restrict__ dnp, const int2* __restrict__ t12,
    const unsigned int* __restrict__ xWp, const unsigned int* __restrict__ rW2p,
    const float* __restrict__ denom2, float* __restrict__ outp) {
  int n = blockIdx.x * 4 + (threadIdx.x >> 6);
  int lane = threadIdx.x & 63;
  int q = lane & 15, g = lane >> 4;
  int s0 = rowstart[n];
  int deg = rowstart[n + 1] - s0;
  int jj = q + 16 * g;
  float r0 = 0.f, r1 = 0.f;
  if (deg > 0) {
    float ac0[4] = {0.f, 0.f, 0.f, 0.f}, ac1[4] = {0.f, 0.f, 0.f, 0.f};
    const int pend = s0 + deg;
    for (int p0 = s0; p0 < pend; p0 += 4) {
      int p = p0 + g;
      float w = 0.f;
      int dne = 0, t1e = 0, t2e = -1;
      if (p < pend) {
        w = wexp2[p];
        dne = dnp[p];
        int2 tt = t12[p];
        t1e = tt.x;
        t2e = tt.y;
      }
      const unsigned int* xr = xWp + (size_t)dne * 128 + 64;
      const unsigned int* rp = rW2p + (size_t)t1e * 64;
#pragma unroll
      for (int k = 0; k < 4; ++k) {
        int j2 = q + 16 * k;
        unsigned int ud = xr[j2];
        unsigned int ur = rp[j2];
        float rv0 = unpk_lo(ur), rv1 = unpk_hi(ur);
        if (t2e >= 0) {
          unsigned int u2 = rW2p[(size_t)t2e * 64 + j2];
          rv0 += unpk_lo(u2);
          rv1 += unpk_hi(u2);
        }
        ac0[k] = fmaf(w, unpk_lo(ud) + rv0, ac0[k]);
        ac1[k] = fmaf(w, unpk_hi(ud) + rv1, ac1[k]);
      }
    }
#pragma unroll
    for (int k = 0; k < 4; ++k) {
      ac0[k] += __shfl_xor(ac0[k], 16, 64);
      ac0[k] += __shfl_xor(ac0[k], 32, 64);
      ac1[k] += __shfl_xor(ac1[k], 16, 64);
      ac1[k] += __shfl_xor(ac1[k], 32, 64);
    }
    float a0g = (g == 0) ? ac0[0] : (g == 1) ? ac0[1] : (g == 2) ? ac0[2] : ac0[3];
    float a1g = (g == 0) ? ac1[0] : (g == 1) ? ac1[1] : (g == 2) ? ac1[2] : ac1[3];
    float d = denom2[n];
    float inv = 1.f / (d + SEPS);
    unsigned int us = xWp[(size_t)n * 128 + jj];
    float o0 = (a0g + d * unpk_lo(us)) * inv;
    float o1 = (a1g + d * unpk_hi(us)) * inv;
    r0 = (o0 > 0.f) ? o0 : __expf(o0) - 1.f;  // final elu
    r1 = (o1 > 0.f) ? o1 : __expf(o1) - 1.f;
  }
  ((float2*)outp)[(size_t)n * 64 + jj] = make_float2(r0, r1);  // cols 2jj, 2jj+1
}

// ---------------- launch ----------------
extern "C" void kernel_launch(void* const* d_in, const int* in_sizes, int n_in, void* d_out,
                              int out_size, void* d_ws, size_t ws_size, hipStream_t stream) {
  const int* edge_index = (const int*)d_in[0];
  const int* srcA = edge_index;
  const int* dstA = edge_index + ETOT;
  const float* x = (const float*)d_in[1];
  const float* r = (const float*)d_in[2];
  const int* et = (const int*)d_in[3];
  const int* et2 = (const int*)d_in[4];
  const float* Wh = (const float*)d_in[5];
  const float* ah = (const float*)d_in[6];
  const float* Wo = (const float*)d_in[7];
  const float* ao = (const float*)d_in[8];
  const float* Wr = (const float*)d_in[9];
  float* out = (float*)d_out;
  float* r2out = out + (size_t)NNODES * 128;

  // workspace layout (256-B aligned chunks)
  char* ws = (char*)d_ws;
  size_t o = 0;
  auto alloc = [&](size_t bytes) {
    char* p = ws + o;
    o += (bytes + 255) & ~(size_t)255;
    return p;
  };
  unsigned int* xWp = (unsigned int*)alloc((size_t)NNODES * 128 * 4);  // plain bf16 rows
  float* sc1 = (float*)alloc((size_t)NNODES * 4 * 4);
  float* sc2 = (float*)alloc((size_t)NNODES * 4 * 4);  // 4 slots, summed in eprep2
  // zero block: cnt (N ints) + denom1 (2N floats) + denom2 (N floats), contiguous
  int* zb = (int*)alloc((size_t)4 * NNODES * 4);
  int* cnt = zb;
  float* denom1 = (float*)(zb + NNODES);
  float* denom2 = (float*)(zb + 3 * NNODES);
  unsigned int* rW1p = (unsigned int*)alloc((size_t)NREL * 64 * 4);
  float* srel1 = (float*)alloc(2 * NREL * 4);
  unsigned int* rW2p = (unsigned int*)alloc((size_t)NREL * 64 * 4);
  float* srel2 = (float*)alloc(NREL * 4);
  unsigned int* x1b = (unsigned int*)alloc((size_t)NNODES * 64 * 4);  // plain bf16 x1
  unsigned short* Wb1 = (unsigned short*)alloc(256 * 128 * 2);
  unsigned short* Wb2 = (unsigned short*)alloc(256 * 128 * 2);
  int* rowstart = (int*)alloc((NNODES + 1) * 4);
  int* cursor = (int*)alloc(NNODES * 4);
  int* blockTot = (int*)alloc(512 * 4);
  int* blockOff = (int*)alloc(512 * 4);
  int* perm = (int*)alloc(ETOT * 4);
  int* srcp = (int*)alloc(ETOT * 4);
  int* dnp = (int*)alloc(ETOT * 4);
  int2* t12 = (int2*)alloc((size_t)ETOT * 8);
  float2* wexp1 = (float2*)alloc((size_t)ETOT * 8);
  float* wexp2 = (float*)alloc(ETOT * 4);

  const int EB = (ETOT + 255) / 256;  // 1250

  // --- zero cnt + denom1 + denom2 in one pass ---
  k_zero_int<<<(4 * NNODES + 255) / 256, 256, 0, stream>>>(zb, 4 * NNODES);

  // --- CSR build ---
  k_count<<<EB, 256, 0, stream>>>(srcA, cnt);
  k_scan_a<<<NB_SCAN, 256, 0, stream>>>(cnt, rowstart, blockTot);
  k_scan_b<<<1, 512, 0, stream>>>(blockTot, blockOff);
  k_scan_c<<<NB_SCAN, 256, 0, stream>>>(rowstart, blockOff, cursor);
  k_scatter<<<EB, 256, 0, stream>>>(srcA, cursor, perm);

  // --- relation precompute + weight staging ---
  k_relprep1<<<NREL, 128, 0, stream>>>(r, Wh, ah, rW1p, srel1);
  k_relprep2f<<<NREL, 128, 0, stream>>>(r, Wr, Wo, ao, rW2p, srel2, r2out);
  k_packb_both<<<512, 128, 0, stream>>>(Wh, Wo, Wb1, Wb2);

  // --- layer 1 ---
  k_gemm_mfma<1><<<GGRID, 256, 0, stream>>>(x, Wb1, ah, xWp, sc1);
  k_eprep1<<<EB, 256, 0, stream>>>(perm, srcA, dstA, et, et2, sc1, srel1, srcp, dnp, t12,
                                   wexp1, denom1);
  k_agg1<<<NNODES / 4, 256, 0, stream>>>(rowstart, wexp1, dnp, t12, xWp, rW1p,
                                         (const float2*)denom1, x1b);

  // --- layer 2 ---
  k_gemm_mfma<2><<<GGRID, 256, 0, stream>>>(x1b, Wb2, ao, xWp, sc2);
  k_eprep2<<<EB, 256, 0, stream>>>(srcp, dnp, t12, sc2, srel2, wexp2, denom2);
  k_agg2<<<NNODES / 4, 256, 0, stream>>>(rowstart, wexp2, dnp, t12, xWp, rW2p, denom2, out);
}

// Round 11
// 392.702 us; speedup vs baseline: 1.0899x; 1.0899x over previous
//
#include <hip/hip_runtime.h>
#include <math.h>

// Problem constants (from reference)
#define NNODES 100000
#define NREL 500
#define E1 288000
#define ETOT 320000
#define LALPHA 0.2f
#define SEPS 1e-16f
#define NB_SCAN ((NNODES + 255) / 256)  // 391 blocks of 256 for the scan
#define GTILES 6250                      // 100000 / 16 row-tiles, exact
#define GTPB 5                           // tiles per block
#define GGRID (GTILES / GTPB)            // 1250 blocks, exact

typedef __attribute__((ext_vector_type(8))) short bf16x8;
typedef __attribute__((ext_vector_type(4))) float f32x4;

// fp32 -> bf16 (round-to-nearest-even), header-independent
__device__ __forceinline__ unsigned short f2bf(float x) {
  unsigned int u = __float_as_uint(x);
  unsigned int r = (u + 0x7fffu + ((u >> 16) & 1u)) >> 16;
  return (unsigned short)r;
}
// pack two fp32 as bf16 pair (lo, hi) in one uint
__device__ __forceinline__ unsigned int packbf2(float lo, float hi) {
  return (unsigned int)f2bf(lo) | ((unsigned int)f2bf(hi) << 16);
}
__device__ __forceinline__ float unpk_lo(unsigned int u) { return __uint_as_float(u << 16); }
__device__ __forceinline__ float unpk_hi(unsigned int u) {
  return __uint_as_float(u & 0xffff0000u);
}
__device__ __forceinline__ float lrelu(float e) { return (e >= 0.f) ? e : LALPHA * e; }
// clamped exp: shift-free softmax weight (logits here are O(1); clamp only for safety)
__device__ __forceinline__ float wexp(float lg) { return __expf(fminf(lg, 60.f)); }

// ---------------- wave (64-lane) reductions ----------------
__device__ __forceinline__ float wave_sum64(float v) {
#pragma unroll
  for (int o = 32; o >= 1; o >>= 1) v += __shfl_xor(v, o, 64);
  return v;
}
// reduce across the 16 lanes of a colv-group (bits 0..3)
__device__ __forceinline__ float red16(float v) {
  v += __shfl_xor(v, 1, 64);
  v += __shfl_xor(v, 2, 64);
  v += __shfl_xor(v, 4, 64);
  v += __shfl_xor(v, 8, 64);
  return v;
}

// ---------------- CSR build ----------------
__global__ void k_zero_int(int* __restrict__ p, int n) {
  int i = blockIdx.x * blockDim.x + threadIdx.x;
  if (i < n) p[i] = 0;
}

__global__ void k_count(const int* __restrict__ src, int* __restrict__ cnt) {
  int e = blockIdx.x * blockDim.x + threadIdx.x;
  if (e < ETOT) atomicAdd(&cnt[src[e]], 1);
}

__global__ void k_scan_a(const int* __restrict__ cnt, int* __restrict__ rowstart,
                         int* __restrict__ blockTot) {
  __shared__ int s[256];
  int t = threadIdx.x;
  int idx = blockIdx.x * 256 + t;
  int v = (idx < NNODES) ? cnt[idx] : 0;
  s[t] = v;
  __syncthreads();
  for (int off = 1; off < 256; off <<= 1) {
    int xv = (t >= off) ? s[t - off] : 0;
    __syncthreads();
    s[t] += xv;
    __syncthreads();
  }
  if (idx < NNODES) rowstart[idx] = s[t] - v;  // exclusive within block
  if (t == 255) blockTot[blockIdx.x] = s[255];
}

__global__ void k_scan_b(const int* __restrict__ blockTot, int* __restrict__ blockOff) {
  __shared__ int s[512];
  int t = threadIdx.x;
  int v = (t < NB_SCAN) ? blockTot[t] : 0;
  s[t] = v;
  __syncthreads();
  for (int off = 1; off < 512; off <<= 1) {
    int xv = (t >= off) ? s[t - off] : 0;
    __syncthreads();
    s[t] += xv;
    __syncthreads();
  }
  if (t < NB_SCAN) blockOff[t] = s[t] - v;  // exclusive
}

__global__ void k_scan_c(int* __restrict__ rowstart, const int* __restrict__ blockOff,
                         int* __restrict__ cursor) {
  int idx = blockIdx.x * 256 + threadIdx.x;
  if (idx < NNODES) {
    int v = rowstart[idx] + blockOff[blockIdx.x];
    rowstart[idx] = v;
    cursor[idx] = v;
  }
  if (idx == 0) rowstart[NNODES] = ETOT;
}

// Scatter edge payload directly into CSR position: no perm indirection downstream.
// et[e] / et2[e-E1] reads are coalesced here (e = thread index).
__global__ void k_scatter(const int* __restrict__ srcA, const int* __restrict__ dstA,
                          const int* __restrict__ et, const int* __restrict__ et2,
                          int* __restrict__ cursor, int* __restrict__ dnp,
                          int2* __restrict__ t12) {
  int e = blockIdx.x * blockDim.x + threadIdx.x;
  if (e < ETOT) {
    int pos = atomicAdd(&cursor[srcA[e]], 1);
    dnp[pos] = dstA[e];
    int t1, t2 = -1;
    if (e < E1) {
      t1 = et[e];
    } else {
      int2 tt = ((const int2*)et2)[e - E1];
      t1 = tt.x;
      t2 = tt.y;
    }
    t12[pos] = make_int2(t1, t2);
  }
}

// ---------------- relation-level precompute ----------------
// rW1p[t][j] = bf16pair(rel[2j], rel[2j+1]), rel = concat(h0 64, h1 64)  (plain layout)
__global__ void k_relprep1(const float* __restrict__ r, const float* __restrict__ Wh,
                           const float* __restrict__ ah, unsigned int* __restrict__ rW1p,
                           float* __restrict__ srel1) {
  __shared__ float vals[128];
  int t = blockIdx.x;    // 0..499
  int tid = threadIdx.x; // 0..127: h = tid>>6, kk = tid&63
  int h = tid >> 6, kk = tid & 63;
  const float* wcol = Wh + h * 24576 + 256 * 64 + kk;
  const float* rrow = r + t * 128;
  float acc = 0.f;
#pragma unroll 4
  for (int d = 0; d < 128; ++d) acc = fmaf(rrow[d], wcol[d * 64], acc);
  vals[tid] = acc;
  float p = wave_sum64(acc * ah[h * 64 + kk]);
  if (kk == 0) srel1[t * 2 + h] = p;
  __syncthreads();
  if (tid < 64) rW1p[t * 64 + tid] = packbf2(vals[2 * tid], vals[2 * tid + 1]);
}

// Fused: r2[t] row (to r2out, LDS) + rW2p pack + srel2
__global__ void k_relprep2f(const float* __restrict__ r, const float* __restrict__ Wr,
                            const float* __restrict__ Wo, const float* __restrict__ ao,
                            unsigned int* __restrict__ rW2p, float* __restrict__ srel2,
                            float* __restrict__ r2out) {
  __shared__ float v2[128];
  __shared__ float s[128];
  __shared__ float vals[128];
  int t = blockIdx.x;   // 0..499
  int k = threadIdx.x;  // 0..127
  float a2 = 0.f;
#pragma unroll 4
  for (int d = 0; d < 128; ++d) a2 = fmaf(r[t * 128 + d], Wr[d * 128 + k], a2);
  r2out[t * 128 + k] = a2;
  v2[k] = a2;
  __syncthreads();
  float acc = 0.f;
#pragma unroll 4
  for (int d = 0; d < 128; ++d) acc = fmaf(v2[d], Wo[(256 + d) * 128 + k], acc);
  vals[k] = acc;
  s[k] = acc * ao[k];
  __syncthreads();
  for (int off = 64; off >= 1; off >>= 1) {
    if (k < off) s[k] += s[k + off];
    __syncthreads();
  }
  if (k == 0) srel2[t] = s[0];
  if (k < 64) rW2p[t * 64 + k] = packbf2(vals[2 * k], vals[2 * k + 1]);
}

// ---------------- MFMA weight packing (both layers, one launch) ----------------
// col order: LAYER1 c = part*128 + h*64 + kc; LAYER2 c = part*128 + kc
__global__ void k_packb_both(const float* __restrict__ Wh, const float* __restrict__ Wo,
                             unsigned short* __restrict__ Wb1,
                             unsigned short* __restrict__ Wb2) {
  int c = blockIdx.x & 255;
  int layer = blockIdx.x >> 8;
  int d = threadIdx.x;  // 0..127
  if (layer == 0) {
    int h = (c >> 6) & 1, part = c >> 7, kc = c & 63;
    Wb1[c * 128 + d] = f2bf(Wh[h * 24576 + (part * 128 + d) * 64 + kc]);
  } else {
    int part = c >> 7, kc = c & 127;
    Wb2[c * 128 + d] = f2bf(Wo[(part * 128 + d) * 128 + kc]);
  }
}

// ---------------- MFMA GEMM: xWp[N][128 uints] (plain bf16 row) = X @ Wb^T ----------------
// Wave owns 64 CONTIGUOUS cols; B resident in 64 VGPR. No LDS/barriers/atomics.
// Per row, wave writes one aligned 128-B chunk. sc slot direct-stored per wave.
template <int LAYER>
__global__ __launch_bounds__(256) void k_gemm_mfma(const void* __restrict__ Xin,
                                                   const unsigned short* __restrict__ Wb,
                                                   const float* __restrict__ avec,
                                                   unsigned int* __restrict__ xWp,
                                                   float* __restrict__ sc) {
  const int lane = threadIdx.x & 63;
  const int wave = threadIdx.x >> 6;
  const int colv = lane & 15;
  const int kg = lane >> 4;

  bf16x8 b[4][4];
#pragma unroll
  for (int t = 0; t < 4; ++t)
#pragma unroll
    for (int s = 0; s < 4; ++s)
      b[t][s] = *(const bf16x8*)(Wb + (size_t)(wave * 64 + t * 16 + colv) * 128 + s * 32 +
                                 kg * 8);
  float av[4];
#pragma unroll
  for (int t = 0; t < 4; ++t) av[t] = avec[(wave & 1) * 64 + t * 16 + colv];
  const int slot = (LAYER == 1) ? (((wave & 1) << 1) | (wave >> 1)) : wave;

  const float4* xf4 = (const float4*)Xin;
  const uint4* xu4 = (const uint4*)Xin;
  int tile = blockIdx.x * GTPB;

  float4 cf[8];
  uint4 cu[4];
  {
    int ar = tile * 16 + colv;
    if (LAYER == 1) {
      int base = ar * 32 + kg * 2;
#pragma unroll
      for (int s = 0; s < 4; ++s) {
        cf[2 * s] = xf4[base + s * 8];
        cf[2 * s + 1] = xf4[base + s * 8 + 1];
      }
    } else {
      int base = ar * 16 + kg;
#pragma unroll
      for (int s = 0; s < 4; ++s) cu[s] = xu4[base + s * 4];
    }
  }

  for (int it = 0; it < GTPB; ++it, ++tile) {
    float4 nf[8];
    uint4 nu[4];
    const bool hasnext = (it + 1 < GTPB);
    if (hasnext) {
      int ar = (tile + 1) * 16 + colv;
      if (LAYER == 1) {
        int base = ar * 32 + kg * 2;
#pragma unroll
        for (int s = 0; s < 4; ++s) {
          nf[2 * s] = xf4[base + s * 8];
          nf[2 * s + 1] = xf4[base + s * 8 + 1];
        }
      } else {
        int base = ar * 16 + kg;
#pragma unroll
        for (int s = 0; s < 4; ++s) nu[s] = xu4[base + s * 4];
      }
    }

    bf16x8 a[4];
    if (LAYER == 1) {
#pragma unroll
      for (int s = 0; s < 4; ++s) {
        union {
          unsigned short us[8];
          bf16x8 v;
        } u;
        u.us[0] = f2bf(cf[2 * s].x); u.us[1] = f2bf(cf[2 * s].y);
        u.us[2] = f2bf(cf[2 * s].z); u.us[3] = f2bf(cf[2 * s].w);
        u.us[4] = f2bf(cf[2 * s + 1].x); u.us[5] = f2bf(cf[2 * s + 1].y);
        u.us[6] = f2bf(cf[2 * s + 1].z); u.us[7] = f2bf(cf[2 * s + 1].w);
        a[s] = u.v;
      }
    } else {
#pragma unroll
      for (int s = 0; s < 4; ++s) {
        union {
          uint4 q;
          bf16x8 v;
        } u;
        u.q = cu[s];
        a[s] = u.v;
      }
    }

    f32x4 acc[4];
#pragma unroll
    for (int t = 0; t < 4; ++t) acc[t] = (f32x4){0.f, 0.f, 0.f, 0.f};
#pragma unroll
    for (int s = 0; s < 4; ++s)
#pragma unroll
      for (int t = 0; t < 4; ++t)
        acc[t] = __builtin_amdgcn_mfma_f32_16x16x32_bf16(a[s], b[t][s], acc[t], 0, 0, 0);

    const int rbase = tile * 16 + kg * 4;
    const int m = colv >> 1;
    const bool evn = (colv & 1) == 0;
#pragma unroll
    for (int i = 0; i < 4; ++i) {
      unsigned int* orow = xWp + (size_t)(rbase + i) * 128 + wave * 32;
#pragma unroll
      for (int t = 0; t < 4; ++t) {
        float lo = acc[t][i];
        float other = __shfl_xor(lo, 1, 64);
        if (evn) orow[t * 8 + m] = packbf2(lo, other);
      }
      float p = 0.f;
#pragma unroll
      for (int t = 0; t < 4; ++t) p = fmaf(acc[t][i], av[t], p);
      p = red16(p);
      if (colv == 0) sc[(size_t)(rbase + i) * 4 + slot] = p;
    }

    if (hasnext) {
      if (LAYER == 1) {
#pragma unroll
        for (int j = 0; j < 8; ++j) cf[j] = nf[j];
      } else {
#pragma unroll
        for (int j = 0; j < 4; ++j) cu[j] = nu[j];
      }
    }
  }
}

// ---------------- layer-1 aggregation: fused w-compute + weighted gather ----------------
// Plain layout: uint j of a row = cols (2j, 2j+1). k<2 -> head0 cols, k>=2 -> head1.
// Denominator = in-wave sum of w (max-free softmax) -> no eprep pass, no atomics.
__global__ __launch_bounds__(256) void k_agg1(
    const int* __restrict__ rowstart, const int* __restrict__ dnp,
    const int2* __restrict__ t12, const unsigned int* __restrict__ xWp,
    const unsigned int* __restrict__ rW1p, const float* __restrict__ sc1,
    const float2* __restrict__ srel1, unsigned int* __restrict__ x1b) {
  int n = blockIdx.x * 4 + (threadIdx.x >> 6);
  int lane = threadIdx.x & 63;
  int q = lane & 15, g = lane >> 4;
  int s0 = rowstart[n];
  int deg = rowstart[n + 1] - s0;
  int jj = q + 16 * g;
  float r0 = 0.f, r1 = 0.f;
  if (deg > 0) {
    float4 scn = ((const float4*)sc1)[n];  // {ss_h0, sd_h0, ss_h1, sd_h1}, wave-uniform
    const float ss0 = scn.x, ss1 = scn.z;
    float ac0[4] = {0.f, 0.f, 0.f, 0.f}, ac1[4] = {0.f, 0.f, 0.f, 0.f};
    float dsum0 = 0.f, dsum1 = 0.f;
    const int pend = s0 + deg;
    for (int p0 = s0; p0 < pend; p0 += 4) {
      int p = p0 + g;  // this group's edge
      float w0 = 0.f, w1 = 0.f;
      int dne = 0, t1e = 0, t2e = -1;
      if (p < pend) {
        dne = dnp[p];  // 16-lane same-address broadcast loads
        int2 tt = t12[p];
        t1e = tt.x;
        t2e = tt.y;
        float2 sr = srel1[t1e];
        float rel0 = sr.x, rel1 = sr.y;
        if (t2e >= 0) {
          float2 sb = srel1[t2e];
          rel0 += sb.x;
          rel1 += sb.y;
        }
        float4 sdv = ((const float4*)sc1)[dne];
        w0 = wexp(lrelu(ss0 + sdv.y + rel0));
        w1 = wexp(lrelu(ss1 + sdv.w + rel1));
        dsum0 += w0;
        dsum1 += w1;
      }
      const unsigned int* xr = xWp + (size_t)dne * 128 + 64;
      const unsigned int* rp = rW1p + (size_t)t1e * 64;
#pragma unroll
      for (int k = 0; k < 4; ++k) {
        int j2 = q + 16 * k;
        float as = (k < 2) ? w0 : w1;  // head by col range (compile-time per k)
        unsigned int ud = xr[j2];
        unsigned int ur = rp[j2];
        float rv0 = unpk_lo(ur), rv1 = unpk_hi(ur);
        if (t2e >= 0) {  // group-uniform branch
          unsigned int u2 = rW1p[(size_t)t2e * 64 + j2];
          rv0 += unpk_lo(u2);
          rv1 += unpk_hi(u2);
        }
        ac0[k] = fmaf(as, unpk_lo(ud) + rv0, ac0[k]);
        ac1[k] = fmaf(as, unpk_hi(ud) + rv1, ac1[k]);
      }
    }
    // reduce across the 4 groups (lanes q, q+16, q+32, q+48)
#pragma unroll
    for (int k = 0; k < 4; ++k) {
      ac0[k] += __shfl_xor(ac0[k], 16, 64);
      ac0[k] += __shfl_xor(ac0[k], 32, 64);
      ac1[k] += __shfl_xor(ac1[k], 16, 64);
      ac1[k] += __shfl_xor(ac1[k], 32, 64);
    }
    dsum0 += __shfl_xor(dsum0, 16, 64);
    dsum0 += __shfl_xor(dsum0, 32, 64);
    dsum1 += __shfl_xor(dsum1, 16, 64);
    dsum1 += __shfl_xor(dsum1, 32, 64);
    float a0g = (g == 0) ? ac0[0] : (g == 1) ? ac0[1] : (g == 2) ? ac0[2] : ac0[3];
    float a1g = (g == 0) ? ac1[0] : (g == 1) ? ac1[1] : (g == 2) ? ac1[2] : ac1[3];
    float dsel = (g < 2) ? dsum0 : dsum1;
    float isel = 1.f / (dsel + SEPS);
    unsigned int us = xWp[(size_t)n * 128 + jj];
    float o0 = (a0g + dsel * unpk_lo(us)) * isel;
    float o1 = (a1g + dsel * unpk_hi(us)) * isel;
    r0 = (o0 > 0.f) ? o0 : __expf(o0) - 1.f;  // elu (concat=True)
    r1 = (o1 > 0.f) ? o1 : __expf(o1) - 1.f;
  }
  x1b[(size_t)n * 64 + jj] = packbf2(r0, r1);  // plain bf16 row (cols 2jj, 2jj+1)
}

// ---------------- layer-2 aggregation: same structure, fp32 out ----------------
// sc2[n] = {p0a, p0b, p1a, p1b}: ss = p0a+p0b, sd = p1a+p1b
__global__ __launch_bounds__(256) void k_agg2(
    const int* __restrict__ rowstart, const int* __restrict__ dnp,
    const int2* __restrict__ t12, const unsigned int* __restrict__ xWp,
    const unsigned int* __restrict__ rW2p, const float* __restrict__ sc2,
    const float* __restrict__ srel2, float* __restrict__ outp) {
  int n = blockIdx.x * 4 + (threadIdx.x >> 6);
  int lane = threadIdx.x & 63;
  int q = lane & 15, g = lane >> 4;
  int s0 = rowstart[n];
  int deg = rowstart[n + 1] - s0;
  int jj = q + 16 * g;
  float r0 = 0.f, r1 = 0.f;
  if (deg > 0) {
    float4 scn = ((const float4*)sc2)[n];
    const float ss = scn.x + scn.y;  // src-part scalar, wave-uniform
    float ac0[4] = {0.f, 0.f, 0.f, 0.f}, ac1[4] = {0.f, 0.f, 0.f, 0.f};
    float dsum = 0.f;
    const int pend = s0 + deg;
    for (int p0 = s0; p0 < pend; p0 += 4) {
      int p = p0 + g;
      float w = 0.f;
      int dne = 0, t1e = 0, t2e = -1;
      if (p < pend) {
        dne = dnp[p];
        int2 tt = t12[p];
        t1e = tt.x;
        t2e = tt.y;
        float rel = srel2[t1e];
        if (t2e >= 0) rel += srel2[t2e];
        float4 sdv = ((const float4*)sc2)[dne];
        w = wexp(lrelu(ss + (sdv.z + sdv.w) + rel));
        dsum += w;
      }
      const unsigned int* xr = xWp + (size_t)dne * 128 + 64;
      const unsigned int* rp = rW2p + (size_t)t1e * 64;
#pragma unroll
      for (int k = 0; k < 4; ++k) {
        int j2 = q + 16 * k;
        unsigned int ud = xr[j2];
        unsigned int ur = rp[j2];
        float rv0 = unpk_lo(ur), rv1 = unpk_hi(ur);
        if (t2e >= 0) {
          unsigned int u2 = rW2p[(size_t)t2e * 64 + j2];
          rv0 += unpk_lo(u2);
          rv1 += unpk_hi(u2);
        }
        ac0[k] = fmaf(w, unpk_lo(ud) + rv0, ac0[k]);
        ac1[k] = fmaf(w, unpk_hi(ud) + rv1, ac1[k]);
      }
    }
#pragma unroll
    for (int k = 0; k < 4; ++k) {
      ac0[k] += __shfl_xor(ac0[k], 16, 64);
      ac0[k] += __shfl_xor(ac0[k], 32, 64);
      ac1[k] += __shfl_xor(ac1[k], 16, 64);
      ac1[k] += __shfl_xor(ac1[k], 32, 64);
    }
    dsum += __shfl_xor(dsum, 16, 64);
    dsum += __shfl_xor(dsum, 32, 64);
    float a0g = (g == 0) ? ac0[0] : (g == 1) ? ac0[1] : (g == 2) ? ac0[2] : ac0[3];
    float a1g = (g == 0) ? ac1[0] : (g == 1) ? ac1[1] : (g == 2) ? ac1[2] : ac1[3];
    float inv = 1.f / (dsum + SEPS);
    unsigned int us = xWp[(size_t)n * 128 + jj];
    float o0 = (a0g + dsum * unpk_lo(us)) * inv;
    float o1 = (a1g + dsum * unpk_hi(us)) * inv;
    r0 = (o0 > 0.f) ? o0 : __expf(o0) - 1.f;  // final elu
    r1 = (o1 > 0.f) ? o1 : __expf(o1) - 1.f;
  }
  ((float2*)outp)[(size_t)n * 64 + jj] = make_float2(r0, r1);  // cols 2jj, 2jj+1
}

// ---------------- launch ----------------
extern "C" void kernel_launch(void* const* d_in, const int* in_sizes, int n_in, void* d_out,
                              int out_size, void* d_ws, size_t ws_size, hipStream_t stream) {
  const int* edge_index = (const int*)d_in[0];
  const int* srcA = edge_index;
  const int* dstA = edge_index + ETOT;
  const float* x = (const float*)d_in[1];
  const float* r = (const float*)d_in[2];
  const int* et = (const int*)d_in[3];
  const int* et2 = (const int*)d_in[4];
  const float* Wh = (const float*)d_in[5];
  const float* ah = (const float*)d_in[6];
  const float* Wo = (const float*)d_in[7];
  const float* ao = (const float*)d_in[8];
  const float* Wr = (const float*)d_in[9];
  float* out = (float*)d_out;
  float* r2out = out + (size_t)NNODES * 128;

  // workspace layout (256-B aligned chunks)
  char* ws = (char*)d_ws;
  size_t o = 0;
  auto alloc = [&](size_t bytes) {
    char* p = ws + o;
    o += (bytes + 255) & ~(size_t)255;
    return p;
  };
  unsigned int* xWp = (unsigned int*)alloc((size_t)NNODES * 128 * 4);  // plain bf16 rows
  float* sc1 = (float*)alloc((size_t)NNODES * 4 * 4);
  float* sc2 = (float*)alloc((size_t)NNODES * 4 * 4);  // 4 slots, summed in agg2
  unsigned int* rW1p = (unsigned int*)alloc((size_t)NREL * 64 * 4);
  float* srel1 = (float*)alloc(2 * NREL * 4);
  unsigned int* rW2p = (unsigned int*)alloc((size_t)NREL * 64 * 4);
  float* srel2 = (float*)alloc(NREL * 4);
  unsigned int* x1b = (unsigned int*)alloc((size_t)NNODES * 64 * 4);  // plain bf16 x1
  unsigned short* Wb1 = (unsigned short*)alloc(256 * 128 * 2);
  unsigned short* Wb2 = (unsigned short*)alloc(256 * 128 * 2);
  int* cnt = (int*)alloc(NNODES * 4);
  int* rowstart = (int*)alloc((NNODES + 1) * 4);
  int* cursor = (int*)alloc(NNODES * 4);
  int* blockTot = (int*)alloc(512 * 4);
  int* blockOff = (int*)alloc(512 * 4);
  int* dnp = (int*)alloc(ETOT * 4);
  int2* t12 = (int2*)alloc((size_t)ETOT * 8);

  const int EB = (ETOT + 255) / 256;  // 1250

  // --- CSR build (payload scattered in k_scatter; no perm) ---
  k_zero_int<<<(NNODES + 255) / 256, 256, 0, stream>>>(cnt, NNODES);
  k_count<<<EB, 256, 0, stream>>>(srcA, cnt);
  k_scan_a<<<NB_SCAN, 256, 0, stream>>>(cnt, rowstart, blockTot);
  k_scan_b<<<1, 512, 0, stream>>>(blockTot, blockOff);
  k_scan_c<<<NB_SCAN, 256, 0, stream>>>(rowstart, blockOff, cursor);
  k_scatter<<<EB, 256, 0, stream>>>(srcA, dstA, et, et2, cursor, dnp, t12);

  // --- relation precompute + weight staging ---
  k_relprep1<<<NREL, 128, 0, stream>>>(r, Wh, ah, rW1p, srel1);
  k_relprep2f<<<NREL, 128, 0, stream>>>(r, Wr, Wo, ao, rW2p, srel2, r2out);
  k_packb_both<<<512, 128, 0, stream>>>(Wh, Wo, Wb1, Wb2);

  // --- layer 1 ---
  k_gemm_mfma<1><<<GGRID, 256, 0, stream>>>(x, Wb1, ah, xWp, sc1);
  k_agg1<<<NNODES / 4, 256, 0, stream>>>(rowstart, dnp, t12, xWp, rW1p, sc1,
                                         (const float2*)srel1, x1b);

  // --- layer 2 ---
  k_gemm_mfma<2><<<GGRID, 256, 0, stream>>>(x1b, Wb2, ao, xWp, sc2);
  k_agg2<<<NNODES / 4, 256, 0, stream>>>(rowstart, dnp, t12, xWp, rW2p, sc2, srel2, out);
}

// Round 12
// 348.663 us; speedup vs baseline: 1.2275x; 1.1263x over previous
//
#include <hip/hip_runtime.h>
#include <math.h>

// Problem constants (from reference)
#define NNODES 100000
#define NREL 500
#define E1 288000
#define ETOT 320000
#define LALPHA 0.2f
#define SEPS 1e-16f
#define NB_SCAN ((NNODES + 255) / 256)  // 391 blocks of 256 for the scan
#define GTILES 6250                      // 100000 / 16 row-tiles, exact
#define GTPB 5                           // tiles per block
#define GGRID (GTILES / GTPB)            // 1250 blocks, exact
#define EB 1250                          // 320000 / 256, exact

typedef __attribute__((ext_vector_type(8))) short bf16x8;
typedef __attribute__((ext_vector_type(4))) float f32x4;

// fp32 -> bf16 (round-to-nearest-even), header-independent
__device__ __forceinline__ unsigned short f2bf(float x) {
  unsigned int u = __float_as_uint(x);
  unsigned int r = (u + 0x7fffu + ((u >> 16) & 1u)) >> 16;
  return (unsigned short)r;
}
// pack two fp32 as bf16 pair (lo, hi) in one uint
__device__ __forceinline__ unsigned int packbf2(float lo, float hi) {
  return (unsigned int)f2bf(lo) | ((unsigned int)f2bf(hi) << 16);
}
__device__ __forceinline__ float unpk_lo(unsigned int u) { return __uint_as_float(u << 16); }
__device__ __forceinline__ float unpk_hi(unsigned int u) {
  return __uint_as_float(u & 0xffff0000u);
}
__device__ __forceinline__ float lrelu(float e) { return (e >= 0.f) ? e : LALPHA * e; }
// clamped exp: shift-free softmax weight (logits here are O(1); clamp only for safety)
__device__ __forceinline__ float wexp(float lg) { return __expf(fminf(lg, 60.f)); }

// ---------------- wave (64-lane) reductions ----------------
__device__ __forceinline__ float wave_sum64(float v) {
#pragma unroll
  for (int o = 32; o >= 1; o >>= 1) v += __shfl_xor(v, o, 64);
  return v;
}
// reduce across the 16 lanes of a colv-group (bits 0..3)
__device__ __forceinline__ float red16(float v) {
  v += __shfl_xor(v, 1, 64);
  v += __shfl_xor(v, 2, 64);
  v += __shfl_xor(v, 4, 64);
  v += __shfl_xor(v, 8, 64);
  return v;
}

// ---------------- CSR scan ----------------
__global__ void k_zero_int(int* __restrict__ p, int n) {
  int i = blockIdx.x * blockDim.x + threadIdx.x;
  if (i < n) p[i] = 0;
}

__global__ void k_scan_a(const int* __restrict__ cnt, int* __restrict__ rowstart,
                         int* __restrict__ blockTot) {
  __shared__ int s[256];
  int t = threadIdx.x;
  int idx = blockIdx.x * 256 + t;
  int v = (idx < NNODES) ? cnt[idx] : 0;
  s[t] = v;
  __syncthreads();
  for (int off = 1; off < 256; off <<= 1) {
    int xv = (t >= off) ? s[t - off] : 0;
    __syncthreads();
    s[t] += xv;
    __syncthreads();
  }
  if (idx < NNODES) rowstart[idx] = s[t] - v;  // exclusive within block
  if (t == 255) blockTot[blockIdx.x] = s[255];
}

__global__ void k_scan_b(const int* __restrict__ blockTot, int* __restrict__ blockOff) {
  __shared__ int s[512];
  int t = threadIdx.x;
  int v = (t < NB_SCAN) ? blockTot[t] : 0;
  s[t] = v;
  __syncthreads();
  for (int off = 1; off < 512; off <<= 1) {
    int xv = (t >= off) ? s[t - off] : 0;
    __syncthreads();
    s[t] += xv;
    __syncthreads();
  }
  if (t < NB_SCAN) blockOff[t] = s[t] - v;  // exclusive
}

__global__ void k_scan_c(int* __restrict__ rowstart, const int* __restrict__ blockOff,
                         int* __restrict__ cursor) {
  int idx = blockIdx.x * 256 + threadIdx.x;
  if (idx < NNODES) {
    int v = rowstart[idx] + blockOff[blockIdx.x];
    rowstart[idx] = v;
    cursor[idx] = v;
  }
  if (idx == 0) rowstart[NNODES] = ETOT;
}

// ---------------- fused prep: count | relprep1 | relprep2f | packb ----------------
// blocks [0,1250): edge count; [1250,1500): relprep1 (2 rel/blk);
// [1500,1750): relprep2f (2 rel/blk); [1750,2006): packb (2 c-slots/blk).
#define PREP_GRID (EB + 250 + 250 + 256)
__global__ __launch_bounds__(256) void k_prep(
    const int* __restrict__ srcA, int* __restrict__ cnt, const float* __restrict__ r,
    const float* __restrict__ Wh, const float* __restrict__ ah,
    unsigned int* __restrict__ rW1p, float* __restrict__ srel1,
    const float* __restrict__ Wr, const float* __restrict__ Wo,
    const float* __restrict__ ao, unsigned int* __restrict__ rW2p,
    float* __restrict__ srel2, float* __restrict__ r2out,
    unsigned short* __restrict__ Wb1, unsigned short* __restrict__ Wb2) {
  __shared__ float sm[6 * 128];
  const int b = blockIdx.x;
  const int tid = threadIdx.x;
  if (b < EB) {
    // ---- edge count ----
    int e = b * 256 + tid;
    if (e < ETOT) atomicAdd(&cnt[srcA[e]], 1);
  } else if (b < EB + 250) {
    // ---- relprep1: rW1p + srel1 ----
    float(*vals)[128] = (float(*)[128])sm;
    int rsel = tid >> 7, tid2 = tid & 127;
    int t = (b - EB) * 2 + rsel;
    int h = tid2 >> 6, kk = tid2 & 63;
    const float* wcol = Wh + h * 24576 + 256 * 64 + kk;
    const float* rrow = r + t * 128;
    float acc = 0.f;
#pragma unroll 4
    for (int d = 0; d < 128; ++d) acc = fmaf(rrow[d], wcol[d * 64], acc);
    vals[rsel][tid2] = acc;
    float p = wave_sum64(acc * ah[h * 64 + kk]);
    if (kk == 0) srel1[t * 2 + h] = p;
    __syncthreads();
    if (tid2 < 64) rW1p[t * 64 + tid2] = packbf2(vals[rsel][2 * tid2], vals[rsel][2 * tid2 + 1]);
  } else if (b < EB + 500) {
    // ---- relprep2f: r2 + rW2p + srel2 ----
    float(*v2)[128] = (float(*)[128])sm;
    float(*s)[128] = (float(*)[128])(sm + 2 * 128);
    float(*vals)[128] = (float(*)[128])(sm + 4 * 128);
    int rsel = tid >> 7, k = tid & 127;
    int t = (b - EB - 250) * 2 + rsel;
    float a2 = 0.f;
#pragma unroll 4
    for (int d = 0; d < 128; ++d) a2 = fmaf(r[t * 128 + d], Wr[d * 128 + k], a2);
    r2out[t * 128 + k] = a2;
    v2[rsel][k] = a2;
    __syncthreads();
    float acc = 0.f;
#pragma unroll 4
    for (int d = 0; d < 128; ++d) acc = fmaf(v2[rsel][d], Wo[(256 + d) * 128 + k], acc);
    vals[rsel][k] = acc;
    s[rsel][k] = acc * ao[k];
    __syncthreads();
    for (int off = 64; off >= 1; off >>= 1) {
      if (k < off) s[rsel][k] += s[rsel][k + off];
      __syncthreads();
    }
    if (k == 0) srel2[t] = s[rsel][0];
    if (k < 64) rW2p[t * 64 + k] = packbf2(vals[rsel][2 * k], vals[rsel][2 * k + 1]);
  } else {
    // ---- packb: both layers ----
    int idx = (b - EB - 500) * 2 + (tid >> 7);  // 0..511
    int layer = idx >> 8, c = idx & 255, d = tid & 127;
    if (layer == 0) {
      int h = (c >> 6) & 1, part = c >> 7, kc = c & 63;
      Wb1[c * 128 + d] = f2bf(Wh[h * 24576 + (part * 128 + d) * 64 + kc]);
    } else {
      int part = c >> 7, kc = c & 127;
      Wb2[c * 128 + d] = f2bf(Wo[(part * 128 + d) * 128 + kc]);
    }
  }
}

// ---------------- MFMA GEMM body: xWp[N][128 uints] (plain bf16 row) = X @ Wb^T --------
// Wave owns 64 CONTIGUOUS cols; B resident in 64 VGPR. No LDS/barriers/atomics.
template <int LAYER>
__device__ __forceinline__ void gemm_body(int bid, const void* __restrict__ Xin,
                                          const unsigned short* __restrict__ Wb,
                                          const float* __restrict__ avec,
                                          unsigned int* __restrict__ xWp,
                                          float* __restrict__ sc) {
  const int lane = threadIdx.x & 63;
  const int wave = threadIdx.x >> 6;
  const int colv = lane & 15;
  const int kg = lane >> 4;

  bf16x8 b[4][4];
#pragma unroll
  for (int t = 0; t < 4; ++t)
#pragma unroll
    for (int s = 0; s < 4; ++s)
      b[t][s] = *(const bf16x8*)(Wb + (size_t)(wave * 64 + t * 16 + colv) * 128 + s * 32 +
                                 kg * 8);
  float av[4];
#pragma unroll
  for (int t = 0; t < 4; ++t) av[t] = avec[(wave & 1) * 64 + t * 16 + colv];
  const int slot = (LAYER == 1) ? (((wave & 1) << 1) | (wave >> 1)) : wave;

  const float4* xf4 = (const float4*)Xin;
  const uint4* xu4 = (const uint4*)Xin;
  int tile = bid * GTPB;

  float4 cf[8];
  uint4 cu[4];
  {
    int ar = tile * 16 + colv;
    if (LAYER == 1) {
      int base = ar * 32 + kg * 2;
#pragma unroll
      for (int s = 0; s < 4; ++s) {
        cf[2 * s] = xf4[base + s * 8];
        cf[2 * s + 1] = xf4[base + s * 8 + 1];
      }
    } else {
      int base = ar * 16 + kg;
#pragma unroll
      for (int s = 0; s < 4; ++s) cu[s] = xu4[base + s * 4];
    }
  }

  for (int it = 0; it < GTPB; ++it, ++tile) {
    float4 nf[8];
    uint4 nu[4];
    const bool hasnext = (it + 1 < GTPB);
    if (hasnext) {
      int ar = (tile + 1) * 16 + colv;
      if (LAYER == 1) {
        int base = ar * 32 + kg * 2;
#pragma unroll
        for (int s = 0; s < 4; ++s) {
          nf[2 * s] = xf4[base + s * 8];
          nf[2 * s + 1] = xf4[base + s * 8 + 1];
        }
      } else {
        int base = ar * 16 + kg;
#pragma unroll
        for (int s = 0; s < 4; ++s) nu[s] = xu4[base + s * 4];
      }
    }

    bf16x8 a[4];
    if (LAYER == 1) {
#pragma unroll
      for (int s = 0; s < 4; ++s) {
        union {
          unsigned short us[8];
          bf16x8 v;
        } u;
        u.us[0] = f2bf(cf[2 * s].x); u.us[1] = f2bf(cf[2 * s].y);
        u.us[2] = f2bf(cf[2 * s].z); u.us[3] = f2bf(cf[2 * s].w);
        u.us[4] = f2bf(cf[2 * s + 1].x); u.us[5] = f2bf(cf[2 * s + 1].y);
        u.us[6] = f2bf(cf[2 * s + 1].z); u.us[7] = f2bf(cf[2 * s + 1].w);
        a[s] = u.v;
      }
    } else {
#pragma unroll
      for (int s = 0; s < 4; ++s) {
        union {
          uint4 q;
          bf16x8 v;
        } u;
        u.q = cu[s];
        a[s] = u.v;
      }
    }

    f32x4 acc[4];
#pragma unroll
    for (int t = 0; t < 4; ++t) acc[t] = (f32x4){0.f, 0.f, 0.f, 0.f};
#pragma unroll
    for (int s = 0; s < 4; ++s)
#pragma unroll
      for (int t = 0; t < 4; ++t)
        acc[t] = __builtin_amdgcn_mfma_f32_16x16x32_bf16(a[s], b[t][s], acc[t], 0, 0, 0);

    const int rbase = tile * 16 + kg * 4;
    const int m = colv >> 1;
    const bool evn = (colv & 1) == 0;
#pragma unroll
    for (int i = 0; i < 4; ++i) {
      unsigned int* orow = xWp + (size_t)(rbase + i) * 128 + wave * 32;
#pragma unroll
      for (int t = 0; t < 4; ++t) {
        float lo = acc[t][i];
        float other = __shfl_xor(lo, 1, 64);
        if (evn) orow[t * 8 + m] = packbf2(lo, other);
      }
      float p = 0.f;
#pragma unroll
      for (int t = 0; t < 4; ++t) p = fmaf(acc[t][i], av[t], p);
      p = red16(p);
      if (colv == 0) sc[(size_t)(rbase + i) * 4 + slot] = p;
    }

    if (hasnext) {
      if (LAYER == 1) {
#pragma unroll
        for (int j = 0; j < 8; ++j) cf[j] = nf[j];
      } else {
#pragma unroll
        for (int j = 0; j < 4; ++j) cu[j] = nu[j];
      }
    }
  }
}

// ---------------- fused scatter | gemm1 ----------------
// blocks [0,EB): scatter edge payload into CSR position; [EB, EB+GGRID): layer-1 GEMM.
__global__ __launch_bounds__(256) void k_sg1(
    const int* __restrict__ srcA, const int* __restrict__ dstA, const int* __restrict__ et,
    const int* __restrict__ et2, int* __restrict__ cursor, int* __restrict__ dnp,
    int2* __restrict__ t12, const float* __restrict__ x,
    const unsigned short* __restrict__ Wb1, const float* __restrict__ ah,
    unsigned int* __restrict__ xWp, float* __restrict__ sc1) {
  if (blockIdx.x < EB) {
    int e = blockIdx.x * 256 + threadIdx.x;
    if (e < ETOT) {
      int pos = atomicAdd(&cursor[srcA[e]], 1);
      dnp[pos] = dstA[e];
      int t1, t2 = -1;
      if (e < E1) {
        t1 = et[e];
      } else {
        int2 tt = ((const int2*)et2)[e - E1];
        t1 = tt.x;
        t2 = tt.y;
      }
      t12[pos] = make_int2(t1, t2);
    }
  } else {
    gemm_body<1>(blockIdx.x - EB, x, Wb1, ah, xWp, sc1);
  }
}

__global__ __launch_bounds__(256) void k_gemm2(const void* __restrict__ Xin,
                                               const unsigned short* __restrict__ Wb,
                                               const float* __restrict__ avec,
                                               unsigned int* __restrict__ xWp,
                                               float* __restrict__ sc) {
  gemm_body<2>(blockIdx.x, Xin, Wb, avec, xWp, sc);
}

// ---------------- layer-1 aggregation: uint4 gathers, fused w-compute ----------------
// Lane (q,g): group g handles edge p0+g; lane owns dst-half uints 4q..4q+3 (one uint4).
// Head split at q<8 (uints 0..31 = head0). Output uint jo = 4q+g after 4-group reduce.
__global__ __launch_bounds__(256) void k_agg1(
    const int* __restrict__ rowstart, const int* __restrict__ dnp,
    const int2* __restrict__ t12, const unsigned int* __restrict__ xWp,
    const unsigned int* __restrict__ rW1p, const float* __restrict__ sc1,
    const float2* __restrict__ srel1, unsigned int* __restrict__ x1b) {
  int n = blockIdx.x * 4 + (threadIdx.x >> 6);
  int lane = threadIdx.x & 63;
  int q = lane & 15, g = lane >> 4;
  int s0 = rowstart[n];
  int deg = rowstart[n + 1] - s0;
  int jo = 4 * q + g;  // output uint index
  float r0 = 0.f, r1 = 0.f;
  if (deg > 0) {
    float4 scn = ((const float4*)sc1)[n];  // {ss_h0, sd_h0, ss_h1, sd_h1}
    const float ss0 = scn.x, ss1 = scn.z;
    float acL[4] = {0.f, 0.f, 0.f, 0.f}, acH[4] = {0.f, 0.f, 0.f, 0.f};
    float dsum0 = 0.f, dsum1 = 0.f;
    const int pend = s0 + deg;
    for (int p0 = s0; p0 < pend; p0 += 4) {
      int p = p0 + g;  // this group's edge
      float w0 = 0.f, w1 = 0.f;
      int dne = 0, t1e = 0, t2e = -1;
      if (p < pend) {
        dne = dnp[p];  // 16-lane same-address broadcast loads
        int2 tt = t12[p];
        t1e = tt.x;
        t2e = tt.y;
        float2 sr = srel1[t1e];
        float rel0 = sr.x, rel1 = sr.y;
        if (t2e >= 0) {
          float2 sb = srel1[t2e];
          rel0 += sb.x;
          rel1 += sb.y;
        }
        float4 sdv = ((const float4*)sc1)[dne];
        w0 = wexp(lrelu(ss0 + sdv.y + rel0));
        w1 = wexp(lrelu(ss1 + sdv.w + rel1));
        dsum0 += w0;
        dsum1 += w1;
      }
      uint4 xd = *(const uint4*)(xWp + (size_t)dne * 128 + 64 + 4 * q);
      uint4 rv = *(const uint4*)(rW1p + (size_t)t1e * 64 + 4 * q);
      float rL[4] = {unpk_lo(rv.x), unpk_lo(rv.y), unpk_lo(rv.z), unpk_lo(rv.w)};
      float rH[4] = {unpk_hi(rv.x), unpk_hi(rv.y), unpk_hi(rv.z), unpk_hi(rv.w)};
      if (t2e >= 0) {  // group-uniform branch
        uint4 r2v = *(const uint4*)(rW1p + (size_t)t2e * 64 + 4 * q);
        rL[0] += unpk_lo(r2v.x); rH[0] += unpk_hi(r2v.x);
        rL[1] += unpk_lo(r2v.y); rH[1] += unpk_hi(r2v.y);
        rL[2] += unpk_lo(r2v.z); rH[2] += unpk_hi(r2v.z);
        rL[3] += unpk_lo(r2v.w); rH[3] += unpk_hi(r2v.w);
      }
      float wq = (q < 8) ? w0 : w1;  // lane's 4 uints are one head
      acL[0] = fmaf(wq, unpk_lo(xd.x) + rL[0], acL[0]);
      acH[0] = fmaf(wq, unpk_hi(xd.x) + rH[0], acH[0]);
      acL[1] = fmaf(wq, unpk_lo(xd.y) + rL[1], acL[1]);
      acH[1] = fmaf(wq, unpk_hi(xd.y) + rH[1], acH[1]);
      acL[2] = fmaf(wq, unpk_lo(xd.z) + rL[2], acL[2]);
      acH[2] = fmaf(wq, unpk_hi(xd.z) + rH[2], acH[2]);
      acL[3] = fmaf(wq, unpk_lo(xd.w) + rL[3], acL[3]);
      acH[3] = fmaf(wq, unpk_hi(xd.w) + rH[3], acH[3]);
    }
    // reduce across the 4 groups (lanes q, q+16, q+32, q+48)
#pragma unroll
    for (int k = 0; k < 4; ++k) {
      acL[k] += __shfl_xor(acL[k], 16, 64);
      acL[k] += __shfl_xor(acL[k], 32, 64);
      acH[k] += __shfl_xor(acH[k], 16, 64);
      acH[k] += __shfl_xor(acH[k], 32, 64);
    }
    dsum0 += __shfl_xor(dsum0, 16, 64);
    dsum0 += __shfl_xor(dsum0, 32, 64);
    dsum1 += __shfl_xor(dsum1, 16, 64);
    dsum1 += __shfl_xor(dsum1, 32, 64);
    float aL = (g == 0) ? acL[0] : (g == 1) ? acL[1] : (g == 2) ? acL[2] : acL[3];
    float aH = (g == 0) ? acH[0] : (g == 1) ? acH[1] : (g == 2) ? acH[2] : acH[3];
    float dsel = (q < 8) ? dsum0 : dsum1;
    float isel = 1.f / (dsel + SEPS);
    unsigned int us = xWp[(size_t)n * 128 + jo];  // src half
    float o0 = (aL + dsel * unpk_lo(us)) * isel;
    float o1 = (aH + dsel * unpk_hi(us)) * isel;
    r0 = (o0 > 0.f) ? o0 : __expf(o0) - 1.f;  // elu (concat=True)
    r1 = (o1 > 0.f) ? o1 : __expf(o1) - 1.f;
  }
  x1b[(size_t)n * 64 + jo] = packbf2(r0, r1);  // plain bf16 row (cols 2jo, 2jo+1)
}

// ---------------- layer-2 aggregation: same structure, fp32 out ----------------
// sc2[n] = {p0a, p0b, p1a, p1b}: ss = p0a+p0b, sd = p1a+p1b
__global__ __launch_bounds__(256) void k_agg2(
    const int* __restrict__ rowstart, const int* __restrict__ dnp,
    const int2* __restrict__ t12, const unsigned int* __restrict__ xWp,
    const unsigned int* __restrict__ rW2p, const float* __restrict__ sc2,
    const float* __restrict__ srel2, float* __restrict__ outp) {
  int n = blockIdx.x * 4 + (threadIdx.x >> 6);
  int lane = threadIdx.x & 63;
  int q = lane & 15, g = lane >> 4;
  int s0 = rowstart[n];
  int deg = rowstart[n + 1] - s0;
  int jo = 4 * q + g;
  float r0 = 0.f, r1 = 0.f;
  if (deg > 0) {
    float4 scn = ((const float4*)sc2)[n];
    const float ss = scn.x + scn.y;  // src-part scalar, wave-uniform
    float acL[4] = {0.f, 0.f, 0.f, 0.f}, acH[4] = {0.f, 0.f, 0.f, 0.f};
    float dsum = 0.f;
    const int pend = s0 + deg;
    for (int p0 = s0; p0 < pend; p0 += 4) {
      int p = p0 + g;
      float w = 0.f;
      int dne = 0, t1e = 0, t2e = -1;
      if (p < pend) {
        dne = dnp[p];
        int2 tt = t12[p];
        t1e = tt.x;
        t2e = tt.y;
        float rel = srel2[t1e];
        if (t2e >= 0) rel += srel2[t2e];
        float4 sdv = ((const float4*)sc2)[dne];
        w = wexp(lrelu(ss + (sdv.z + sdv.w) + rel));
        dsum += w;
      }
      uint4 xd = *(const uint4*)(xWp + (size_t)dne * 128 + 64 + 4 * q);
      uint4 rv = *(const uint4*)(rW2p + (size_t)t1e * 64 + 4 * q);
      float rL[4] = {unpk_lo(rv.x), unpk_lo(rv.y), unpk_lo(rv.z), unpk_lo(rv.w)};
      float rH[4] = {unpk_hi(rv.x), unpk_hi(rv.y), unpk_hi(rv.z), unpk_hi(rv.w)};
      if (t2e >= 0) {
        uint4 r2v = *(const uint4*)(rW2p + (size_t)t2e * 64 + 4 * q);
        rL[0] += unpk_lo(r2v.x); rH[0] += unpk_hi(r2v.x);
        rL[1] += unpk_lo(r2v.y); rH[1] += unpk_hi(r2v.y);
        rL[2] += unpk_lo(r2v.z); rH[2] += unpk_hi(r2v.z);
        rL[3] += unpk_lo(r2v.w); rH[3] += unpk_hi(r2v.w);
      }
      acL[0] = fmaf(w, unpk_lo(xd.x) + rL[0], acL[0]);
      acH[0] = fmaf(w, unpk_hi(xd.x) + rH[0], acH[0]);
      acL[1] = fmaf(w, unpk_lo(xd.y) + rL[1], acL[1]);
      acH[1] = fmaf(w, unpk_hi(xd.y) + rH[1], acH[1]);
      acL[2] = fmaf(w, unpk_lo(xd.z) + rL[2], acL[2]);
      acH[2] = fmaf(w, unpk_hi(xd.z) + rH[2], acH[2]);
      acL[3] = fmaf(w, unpk_lo(xd.w) + rL[3], acL[3]);
      acH[3] = fmaf(w, unpk_hi(xd.w) + rH[3], acH[3]);
    }
#pragma unroll
    for (int k = 0; k < 4; ++k) {
      acL[k] += __shfl_xor(acL[k], 16, 64);
      acL[k] += __shfl_xor(acL[k], 32, 64);
      acH[k] += __shfl_xor(acH[k], 16, 64);
      acH[k] += __shfl_xor(acH[k], 32, 64);
    }
    dsum += __shfl_xor(dsum, 16, 64);
    dsum += __shfl_xor(dsum, 32, 64);
    float aL = (g == 0) ? acL[0] : (g == 1) ? acL[1] : (g == 2) ? acL[2] : acL[3];
    float aH = (g == 0) ? acH[0] : (g == 1) ? acH[1] : (g == 2) ? acH[2] : acH[3];
    float inv = 1.f / (dsum + SEPS);
    unsigned int us = xWp[(size_t)n * 128 + jo];
    float o0 = (aL + dsum * unpk_lo(us)) * inv;
    float o1 = (aH + dsum * unpk_hi(us)) * inv;
    r0 = (o0 > 0.f) ? o0 : __expf(o0) - 1.f;  // final elu
    r1 = (o1 > 0.f) ? o1 : __expf(o1) - 1.f;
  }
  ((float2*)outp)[(size_t)n * 64 + jo] = make_float2(r0, r1);  // cols 2jo, 2jo+1
}

// ---------------- launch ----------------
extern "C" void kernel_launch(void* const* d_in, const int* in_sizes, int n_in, void* d_out,
                              int out_size, void* d_ws, size_t ws_size, hipStream_t stream) {
  const int* edge_index = (const int*)d_in[0];
  const int* srcA = edge_index;
  const int* dstA = edge_index + ETOT;
  const float* x = (const float*)d_in[1];
  const float* r = (const float*)d_in[2];
  const int* et = (const int*)d_in[3];
  const int* et2 = (const int*)d_in[4];
  const float* Wh = (const float*)d_in[5];
  const float* ah = (const float*)d_in[6];
  const float* Wo = (const float*)d_in[7];
  const float* ao = (const float*)d_in[8];
  const float* Wr = (const float*)d_in[9];
  float* out = (float*)d_out;
  float* r2out = out + (size_t)NNODES * 128;

  // workspace layout (256-B aligned chunks)
  char* ws = (char*)d_ws;
  size_t o = 0;
  auto alloc = [&](size_t bytes) {
    char* p = ws + o;
    o += (bytes + 255) & ~(size_t)255;
    return p;
  };
  unsigned int* xWp = (unsigned int*)alloc((size_t)NNODES * 128 * 4);  // plain bf16 rows
  float* sc1 = (float*)alloc((size_t)NNODES * 4 * 4);
  float* sc2 = (float*)alloc((size_t)NNODES * 4 * 4);  // 4 slots, summed in agg2
  unsigned int* rW1p = (unsigned int*)alloc((size_t)NREL * 64 * 4);
  float* srel1 = (float*)alloc(2 * NREL * 4);
  unsigned int* rW2p = (unsigned int*)alloc((size_t)NREL * 64 * 4);
  float* srel2 = (float*)alloc(NREL * 4);
  unsigned int* x1b = (unsigned int*)alloc((size_t)NNODES * 64 * 4);  // plain bf16 x1
  unsigned short* Wb1 = (unsigned short*)alloc(256 * 128 * 2);
  unsigned short* Wb2 = (unsigned short*)alloc(256 * 128 * 2);
  int* cnt = (int*)alloc(NNODES * 4);
  int* rowstart = (int*)alloc((NNODES + 1) * 4);
  int* cursor = (int*)alloc(NNODES * 4);
  int* blockTot = (int*)alloc(512 * 4);
  int* blockOff = (int*)alloc(512 * 4);
  int* dnp = (int*)alloc(ETOT * 4);
  int2* t12 = (int2*)alloc((size_t)ETOT * 8);

  // 1. zero cnt
  k_zero_int<<<(NNODES + 255) / 256, 256, 0, stream>>>(cnt, NNODES);
  // 2. fused prep: count | relprep1 | relprep2f | packb
  k_prep<<<PREP_GRID, 256, 0, stream>>>(srcA, cnt, r, Wh, ah, rW1p, srel1, Wr, Wo, ao, rW2p,
                                        srel2, r2out, Wb1, Wb2);
  // 3-5. CSR scan
  k_scan_a<<<NB_SCAN, 256, 0, stream>>>(cnt, rowstart, blockTot);
  k_scan_b<<<1, 512, 0, stream>>>(blockTot, blockOff);
  k_scan_c<<<NB_SCAN, 256, 0, stream>>>(rowstart, blockOff, cursor);
  // 6. fused scatter | gemm1
  k_sg1<<<EB + GGRID, 256, 0, stream>>>(srcA, dstA, et, et2, cursor, dnp, t12, x, Wb1, ah,
                                        xWp, sc1);
  // 7. layer-1 aggregation
  k_agg1<<<NNODES / 4, 256, 0, stream>>>(rowstart, dnp, t12, xWp, rW1p, sc1,
                                         (const float2*)srel1, x1b);
  // 8. layer-2 GEMM
  k_gemm2<<<GGRID, 256, 0, stream>>>(x1b, Wb2, ao, xWp, sc2);
  // 9. layer-2 aggregation
  k_agg2<<<NNODES / 4, 256, 0, stream>>>(rowstart, dnp, t12, xWp, rW2p, sc2, srel2, out);
}